// Round 18
// baseline (288.095 us; speedup 1.0000x reference)
//
#include <hip/hip_runtime.h>
#include <math.h>
#include <stdint.h>

#define B_ 32
#define S_ 2048
#define D_ 1024
#define H_ 1024
#define NEGV -1000000000000.0f

typedef __attribute__((ext_vector_type(8))) short bf16x8;
typedef __attribute__((ext_vector_type(8))) _Float16 f16x8;
typedef __attribute__((ext_vector_type(4))) float f32x4;

static __device__ __forceinline__ unsigned short f2bf(float x) {
    union { float f; unsigned u; } v; v.f = x;
    unsigned r = v.u + 0x7FFF + ((v.u >> 16) & 1);
    return (unsigned short)(r >> 16);
}
static __device__ __forceinline__ float bf2f(unsigned short h) {
    union { float f; unsigned u; } v; v.u = ((unsigned)h) << 16; return v.f;
}
static __device__ __forceinline__ unsigned short f2h(float x) {
    _Float16 h = (_Float16)x; unsigned short u;
    __builtin_memcpy(&u, &h, 2); return u;
}
static __device__ __forceinline__ float h2f(unsigned short u) {
    _Float16 h; __builtin_memcpy(&h, &u, 2); return (float)h;
}
static __device__ __forceinline__ float tanh_fast(float x) {
    float e = __expf(2.f * x);
    return 1.f - 2.f / (e + 1.f);
}
static __device__ __forceinline__ void gl_lds16(unsigned short* lds, const unsigned short* g) {
    __builtin_amdgcn_global_load_lds(
        (const __attribute__((address_space(1))) unsigned int*)(const void*)g,
        (__attribute__((address_space(3))) unsigned int*)(void*)lds,
        16, 0, 0);
}

// ---------- We = W[:, D:] -> single fp16 plane, 16-CHUNK-SWIZZLED storage ----------
// within each 128-elem K-group (16 chunks of 8): stored chunk c' = c ^ (row & 15)
__global__ __launch_bounds__(256) void k_W_f16(const float* __restrict__ W,
                                               unsigned short* __restrict__ out) {
    int idx = blockIdx.x * 256 + threadIdx.x;   // 131072 chunks
    int h = idx >> 7, kc = idx & 127;
    const float* src = W + (size_t)h * (2 * D_) + D_ + kc * 8;
    float4 a = *(const float4*)src;
    float4 c4 = *(const float4*)(src + 4);
    float v[8] = {a.x, a.y, a.z, a.w, c4.x, c4.y, c4.z, c4.w};
    unsigned short t[8];
#pragma unroll
    for (int j = 0; j < 8; ++j) t[j] = f2h(v[j]);
    uint4 w;
    w.x = t[0] | ((unsigned)t[1] << 16); w.y = t[2] | ((unsigned)t[3] << 16);
    w.z = t[4] | ((unsigned)t[5] << 16); w.w = t[6] | ((unsigned)t[7] << 16);
    int g = kc >> 4, cc = kc & 15;
    int dst = g * 128 + ((cc ^ (h & 15)) << 3);
    *(uint4*)(out + (size_t)h * D_ + dst) = w;
}

// ---------- h_part (fp32, exact) ----------
__global__ __launch_bounds__(256) void k_hpart(const float* __restrict__ ls,
                                               const float* __restrict__ W,
                                               float* __restrict__ hp) {
    int bh = blockIdx.x * 256 + threadIdx.x;
    int b = bh >> 10, h = bh & 1023;
    const float* lsr = ls + b * D_;
    const float* wr  = W + (size_t)h * (2 * D_);
    float acc = 0.f;
#pragma unroll 4
    for (int d = 0; d < D_; d += 4) {
        float4 a = *(const float4*)(lsr + d);
        float4 w = *(const float4*)(wr + d);
        acc += a.x * w.x + a.y * w.y + a.z * w.z + a.w * w.w;
    }
    hp[bh] = acc;
}

// ---------- main GEMM: BM=128, BN=256, BK=128, single-buffered, fused A-convert ----------
// 8 K-iterations (vs 16): barrier/drain events halve at CONSTANT 64 MFMA/wave
// per barrier-pair (wave tile 64x64, 4 K-slices). acc halves to 64 regs.
// LDS 96KB: A[128][128]f16 (32KB) | B[256][128]f16 (64KB), both [row][16 chunks]
// with stored chunk c' = c ^ (row&15) (2-way bank alias only = free).
// Schedule/iter: [LOAD_A(t+1)] compute(t) ; sync ; WRITE_A + STAGE_B(t+1) ; sync
__global__ __launch_bounds__(512, 2) void k_scores_m128(
    const float* __restrict__ enc,
    const unsigned short* __restrict__ Wf16,
    const float* __restrict__ hp, const float* __restrict__ bias,
    const float* __restrict__ V, float* __restrict__ spart)
{
    extern __shared__ unsigned short smem[];     // 98304 B
    unsigned short* smemA = smem;                // 16384 shorts = 128x128 f16
    unsigned short* smemB = smem + 16384;        // 32768 shorts = 256x128 f16

    const int tid  = threadIdx.x;
    const int lane = tid & 63, wid = tid >> 6;
    const int wm = wid >> 2, wn = wid & 3;       // 2 x 4 waves, wave tile 64x64
    const int l15 = lane & 15, lhi = lane >> 4;

    // XCD-bijective block swizzle (nwg = 2048, 256 per XCD)
    const int bid  = blockIdx.x;
    const int wgid = (bid & 7) * 256 + (bid >> 3);
    const int mt = wgid >> 2, nt = wgid & 3;
    const int m0 = mt * 128;
    const int nt256 = nt * 256;
    const int b = m0 >> 11;

    // B staging: wave covers rows [wid*32, wid*32+32), 8 issues of 4 rows;
    // lane l -> row +(l>>4), stored chunk l&15 (linear copy of stored order)
    const size_t boff = (size_t)(nt256 + wid * 32 + (lane >> 4)) * D_ + (lane & 15) * 8;
    const int ldsb = wid * 4096;                 // 32 rows * 128 shorts

    f32x4 acc[4][4];
#pragma unroll
    for (int i = 0; i < 4; ++i)
#pragma unroll
        for (int j = 0; j < 4; ++j)
            acc[i][j] = (f32x4){0.f, 0.f, 0.f, 0.f};

    const int swz = l15;                         // 4-bit chunk swizzle

    // A reg-staging: piece p = tid + s*512: row = p>>4 (0..127), pc = p&15
    float4 ar0[4], ar1[4];

#define LOAD_A(KOFS) do {                                                           \
    _Pragma("unroll")                                                               \
    for (int s_ = 0; s_ < 4; ++s_) {                                                \
        int p_ = tid + s_ * 512;                                                    \
        int row_ = p_ >> 4, pc_ = p_ & 15;                                          \
        const float* ap_ = enc + (size_t)(m0 + row_) * D_ + (KOFS) + pc_ * 8;       \
        ar0[s_] = *(const float4*)ap_;                                              \
        ar1[s_] = *(const float4*)(ap_ + 4);                                        \
    }                                                                               \
} while (0)
#define WRITE_A() do {                                                              \
    _Pragma("unroll")                                                               \
    for (int s_ = 0; s_ < 4; ++s_) {                                                \
        int p_ = tid + s_ * 512;                                                    \
        int row_ = p_ >> 4, pc_ = p_ & 15;                                          \
        float v_[8] = {ar0[s_].x, ar0[s_].y, ar0[s_].z, ar0[s_].w,                  \
                       ar1[s_].x, ar1[s_].y, ar1[s_].z, ar1[s_].w};                 \
        unsigned short t_[8];                                                       \
        _Pragma("unroll")                                                           \
        for (int j_ = 0; j_ < 8; ++j_) t_[j_] = f2h(v_[j_]);                        \
        uint4 w_;                                                                   \
        w_.x = t_[0] | ((unsigned)t_[1] << 16); w_.y = t_[2] | ((unsigned)t_[3] << 16); \
        w_.z = t_[4] | ((unsigned)t_[5] << 16); w_.w = t_[6] | ((unsigned)t_[7] << 16); \
        *(uint4*)&smemA[row_ * 128 + ((pc_ ^ (row_ & 15)) << 3)] = w_;              \
    }                                                                               \
} while (0)

#define STAGE_B(KOFS) do {                                                          \
    _Pragma("unroll")                                                               \
    for (int j_ = 0; j_ < 8; ++j_)                                                  \
        gl_lds16(&smemB[ldsb + j_ * 512], Wf16 + boff + (size_t)j_ * 4 * D_ + (KOFS)); \
} while (0)

#define LDA(AR, KS) do {                                                            \
    _Pragma("unroll")                                                               \
    for (int fi_ = 0; fi_ < 4; ++fi_) {                                             \
        int row_ = wm * 64 + fi_ * 16 + l15;                                        \
        int ch_  = ((KS) * 4 + lhi) ^ swz;                                          \
        AR[fi_] = *(const f16x8*)&smemA[row_ * 128 + ch_ * 8];                      \
    }                                                                               \
} while (0)
#define LDB(BR, KS) do {                                                            \
    _Pragma("unroll")                                                               \
    for (int fi_ = 0; fi_ < 4; ++fi_) {                                             \
        int row_ = wn * 64 + fi_ * 16 + l15;                                        \
        int ch_  = ((KS) * 4 + lhi) ^ swz;                                          \
        BR[fi_] = *(const f16x8*)&smemB[row_ * 128 + ch_ * 8];                      \
    }                                                                               \
} while (0)
#define MFMA16(AR, BR) do {                                                         \
    _Pragma("unroll")                                                               \
    for (int fi_ = 0; fi_ < 4; ++fi_)                                               \
    _Pragma("unroll")                                                               \
        for (int fj_ = 0; fj_ < 4; ++fj_)                                           \
            acc[fi_][fj_] = __builtin_amdgcn_mfma_f32_16x16x32_f16(                 \
                AR[fi_], BR[fj_], acc[fi_][fj_], 0, 0, 0);                          \
} while (0)

    // ---- prologue: stage tile 0
    LOAD_A(0);
    WRITE_A();
    STAGE_B(0);
    __syncthreads();                      // vmcnt(0)+lgkmcnt(0)+barrier: tile0 visible

    f16x8 a[4], bk[4];
#pragma unroll 1
    for (int t = 0; t < 8; ++t) {
        const int kofs = (t + 1) * 128;

        if (t < 7) LOAD_A(kofs);          // 8 float4 loads issued early

#pragma unroll
        for (int ks = 0; ks < 4; ++ks) {
            LDB(bk, ks);
            LDA(a, ks);
            MFMA16(a, bk);
        }

        __syncthreads();                  // all reads of tile t complete

        if (t < 7) {
            WRITE_A();                    // A(t+1) convert+write
            STAGE_B(kofs);                // B(t+1) gl_lds
        }

        __syncthreads();                  // tile t+1 visible
    }

    // ---- epilogue: tanh + V-weighted reduce
    float hb[4], vv[4];
#pragma unroll
    for (int fn = 0; fn < 4; ++fn) {
        int h = nt256 + wn * 64 + fn * 16 + l15;
        hb[fn] = hp[b * H_ + h] + bias[h];
        vv[fn] = V[h];
    }
    float* s_red = (float*)smem;          // 512 floats, safe after final barrier
#pragma unroll
    for (int fm = 0; fm < 4; ++fm)
#pragma unroll
        for (int rg = 0; rg < 4; ++rg) {
            float rs = 0.f;
#pragma unroll
            for (int fn = 0; fn < 4; ++fn)
                rs += tanh_fast(acc[fm][fn][rg] + hb[fn]) * vv[fn];
            rs += __shfl_xor(rs, 1, 16);
            rs += __shfl_xor(rs, 2, 16);
            rs += __shfl_xor(rs, 4, 16);
            rs += __shfl_xor(rs, 8, 16);
            if (l15 == 0)
                s_red[wn * 128 + wm * 64 + fm * 16 + lhi * 4 + rg] = rs;
        }
    __syncthreads();
    if (tid < 128) {
        float v = s_red[tid] + s_red[128 + tid] + s_red[256 + tid] + s_red[384 + tid];
        spart[(size_t)nt * 65536 + m0 + tid] = v;
    }
#undef LOAD_A
#undef WRITE_A
#undef STAGE_B
#undef LDA
#undef LDB
#undef MFMA16
}

// ---------- fold nt-partials + mask + softmax ----------
__global__ __launch_bounds__(256) void k_softmax_fold(const float* __restrict__ spart,
                                                      const int* __restrict__ mask,
                                                      float* __restrict__ scores_out,
                                                      float* __restrict__ weights) {
    __shared__ float red[8];
    int b = blockIdx.x, tid = threadIdx.x;
    float vals[8];
    float mx = -INFINITY;
#pragma unroll
    for (int i = 0; i < 8; ++i) {
        int m = b * S_ + tid + i * 256;
        float s = spart[m] + spart[65536 + m] + spart[131072 + m] + spart[196608 + m];
        s = (mask[m] == 1) ? s : NEGV;
        scores_out[m] = s;
        vals[i] = s;
        mx = fmaxf(mx, s);
    }
    for (int off = 32; off; off >>= 1) mx = fmaxf(mx, __shfl_xor(mx, off, 64));
    int wave = tid >> 6;
    if ((tid & 63) == 0) red[wave] = mx;
    __syncthreads();
    mx = fmaxf(fmaxf(red[0], red[1]), fmaxf(red[2], red[3]));
    float sum = 0.f;
#pragma unroll
    for (int i = 0; i < 8; ++i) {
        vals[i] = expf(vals[i] - mx);
        sum += vals[i];
    }
    for (int off = 32; off; off >>= 1) sum += __shfl_xor(sum, off, 64);
    if ((tid & 63) == 0) red[4 + wave] = sum;
    __syncthreads();
    sum = red[4] + red[5] + red[6] + red[7];
    float inv = 1.f / sum;
#pragma unroll
    for (int i = 0; i < 8; ++i)
        weights[b * S_ + tid + i * 256] = vals[i] * inv;
}

// ---------- context partials (fp32 enc, skip zero weights) ----------
__global__ __launch_bounds__(256) void k_ctx_partial_f32(const float* __restrict__ weights,
                                                         const float* __restrict__ enc,
                                                         float* __restrict__ part) {
    int b = blockIdx.x >> 4;
    int chunk = blockIdx.x & 15;
    int tid = threadIdx.x;
    int d0 = tid * 4;
    float4 acc = {0.f, 0.f, 0.f, 0.f};
    int s0 = chunk * 128;
    const float* wrow = weights + b * S_;
    for (int s = s0; s < s0 + 128; ++s) {
        float w = wrow[s];
        if (w != 0.f) {
            float4 e = *(const float4*)(enc + (size_t)(b * S_ + s) * D_ + d0);
            acc.x += w * e.x; acc.y += w * e.y; acc.z += w * e.z; acc.w += w * e.w;
        }
    }
    *(float4*)(part + (size_t)blockIdx.x * D_ + d0) = acc;
}

__global__ __launch_bounds__(256) void k_ctx_reduce(const float* __restrict__ part,
                                                    float* __restrict__ ctx) {
    int bd = blockIdx.x * 256 + threadIdx.x;
    int b = bd >> 10, d = bd & 1023;
    float acc = 0.f;
#pragma unroll
    for (int c = 0; c < 16; ++c)
        acc += part[(size_t)(b * 16 + c) * D_ + d];
    ctx[bd] = acc;
}

// ================== fallback path (tiny ws): linear bf16 split + round-2 kernel ==================
__global__ __launch_bounds__(256) void k_splitW_lin(const float* __restrict__ W,
                                                    unsigned short* __restrict__ hi,
                                                    unsigned short* __restrict__ lo) {
    int idx = blockIdx.x * 256 + threadIdx.x;
    int h = idx >> 7, kc = idx & 127;
    const float* src = W + (size_t)h * (2 * D_) + D_ + kc * 8;
    float4 a = *(const float4*)src;
    float4 c = *(const float4*)(src + 4);
    float v[8] = {a.x, a.y, a.z, a.w, c.x, c.y, c.z, c.w};
    unsigned short th[8], tl[8];
#pragma unroll
    for (int j = 0; j < 8; ++j) {
        th[j] = f2bf(v[j]);
        tl[j] = f2bf(v[j] - bf2f(th[j]));
    }
    uint4 hw, lw;
    hw.x = th[0] | ((unsigned)th[1] << 16); hw.y = th[2] | ((unsigned)th[3] << 16);
    hw.z = th[4] | ((unsigned)th[5] << 16); hw.w = th[6] | ((unsigned)th[7] << 16);
    lw.x = tl[0] | ((unsigned)tl[1] << 16); lw.y = tl[2] | ((unsigned)tl[3] << 16);
    lw.z = tl[4] | ((unsigned)tl[5] << 16); lw.w = tl[6] | ((unsigned)tl[7] << 16);
    *(uint4*)(hi + (size_t)h * D_ + kc * 8) = hw;
    *(uint4*)(lo + (size_t)h * D_ + kc * 8) = lw;
}

__global__ __launch_bounds__(256, 2) void k_scores_mfma_fb(
    const float* __restrict__ enc,
    const unsigned short* __restrict__ Whi,
    const unsigned short* __restrict__ Wlo,
    const float* __restrict__ hp,
    const float* __restrict__ bias,
    const float* __restrict__ V,
    const int* __restrict__ mask,
    float* __restrict__ scores_out)
{
    __shared__ __align__(16) unsigned short smem[4 * 8192];
    unsigned short* sAhi = smem;
    unsigned short* sAlo = smem + 8192;
    unsigned short* sBhi = smem + 16384;
    unsigned short* sBlo = smem + 24576;

    const int tid  = threadIdx.x;
    const int lane = tid & 63, wid = tid >> 6;
    const int wr = wid >> 1, wc = wid & 1;
    const int l15 = lane & 15, lhi = lane >> 4;
    const int m0 = blockIdx.x * 128;
    const int b  = m0 >> 11;

    float rowsum[4][4] = {};
    float4 pa[8];
    uint4  pbh[4], pbl[4];

#define STAGE_LOAD(NB, KB) do {                                            \
    _Pragma("unroll")                                                      \
    for (int i_ = 0; i_ < 4; ++i_) {                                       \
        int c_ = tid + i_ * 256;                                           \
        int r_ = c_ >> 3, kc_ = c_ & 7;                                    \
        const float* ap_ = enc + (size_t)(m0 + r_) * D_ + (KB) * 64 + kc_ * 8; \
        pa[2 * i_]     = *(const float4*)ap_;                              \
        pa[2 * i_ + 1] = *(const float4*)(ap_ + 4);                        \
        size_t bo_ = (size_t)((NB) * 128 + r_) * D_ + (KB) * 64 + kc_ * 8; \
        pbh[i_] = *(const uint4*)(Whi + bo_);                              \
        pbl[i_] = *(const uint4*)(Wlo + bo_);                              \
    }                                                                      \
} while (0)

#define STAGE_WRITE() do {                                                 \
    _Pragma("unroll")                                                      \
    for (int i_ = 0; i_ < 4; ++i_) {                                       \
        int c_ = tid + i_ * 256;                                           \
        int sc_ = c_ ^ ((c_ >> 3) & 7);                                    \
        float vv_[8] = {pa[2*i_].x, pa[2*i_].y, pa[2*i_].z, pa[2*i_].w,    \
                        pa[2*i_+1].x, pa[2*i_+1].y, pa[2*i_+1].z, pa[2*i_+1].w}; \
        unsigned short th_[8], tl_[8];                                     \
        _Pragma("unroll")                                                  \
        for (int j_ = 0; j_ < 8; ++j_) {                                   \
            th_[j_] = f2bf(vv_[j_]);                                       \
            tl_[j_] = f2bf(vv_[j_] - bf2f(th_[j_]));                       \
        }                                                                  \
        uint4 hw_, lw_;                                                    \
        hw_.x = th_[0] | ((unsigned)th_[1] << 16); hw_.y = th_[2] | ((unsigned)th_[3] << 16); \
        hw_.z = th_[4] | ((unsigned)th_[5] << 16); hw_.w = th_[6] | ((unsigned)th_[7] << 16); \
        lw_.x = tl_[0] | ((unsigned)tl_[1] << 16); lw_.y = tl_[2] | ((unsigned)tl_[3] << 16); \
        lw_.z = tl_[4] | ((unsigned)tl_[5] << 16); lw_.w = tl_[6] | ((unsigned)tl_[7] << 16); \
        *(uint4*)&sAhi[sc_ * 8] = hw_;                                     \
        *(uint4*)&sAlo[sc_ * 8] = lw_;                                     \
        *(uint4*)&sBhi[sc_ * 8] = pbh[i_];                                 \
        *(uint4*)&sBlo[sc_ * 8] = pbl[i_];                                 \
    }                                                                      \
} while (0)

    STAGE_LOAD(0, 0);

    for (int nb = 0; nb < 8; ++nb) {
        f32x4 acc[4][4];
#pragma unroll
        for (int i = 0; i < 4; ++i)
#pragma unroll
            for (int j = 0; j < 4; ++j)
                acc[i][j] = (f32x4){0.f, 0.f, 0.f, 0.f};

        for (int kb = 0; kb < 16; ++kb) {
            __syncthreads();
            STAGE_WRITE();
            __syncthreads();
            int nkb = kb + 1, nnb = nb;
            if (nkb == 16) { nkb = 0; nnb = nb + 1; }
            if (nnb < 8) STAGE_LOAD(nnb, nkb);

#pragma unroll
            for (int ks = 0; ks < 2; ++ks) {
                bf16x8 bh[4], bl[4];
#pragma unroll
                for (int fn = 0; fn < 4; ++fn) {
                    int rB = wc * 64 + fn * 16 + l15;
                    int ch = (rB * 8 + ks * 4 + lhi) ^ (rB & 7);
                    bh[fn] = *(const bf16x8*)&sBhi[ch * 8];
                    bl[fn] = *(const bf16x8*)&sBlo[ch * 8];
                }
#pragma unroll
                for (int fm = 0; fm < 4; ++fm) {
                    int rA = wr * 64 + fm * 16 + l15;
                    int ch = (rA * 8 + ks * 4 + lhi) ^ (rA & 7);
                    bf16x8 ah = *(const bf16x8*)&sAhi[ch * 8];
                    bf16x8 al = *(const bf16x8*)&sAlo[ch * 8];
#pragma unroll
                    for (int fn = 0; fn < 4; ++fn) {
                        acc[fm][fn] = __builtin_amdgcn_mfma_f32_16x16x32_bf16(ah, bh[fn], acc[fm][fn], 0, 0, 0);
                        acc[fm][fn] = __builtin_amdgcn_mfma_f32_16x16x32_bf16(ah, bl[fn], acc[fm][fn], 0, 0, 0);
                        acc[fm][fn] = __builtin_amdgcn_mfma_f32_16x16x32_bf16(al, bh[fn], acc[fm][fn], 0, 0, 0);
                    }
                }
            }
        }

        int n0 = nb * 128;
#pragma unroll
        for (int fn = 0; fn < 4; ++fn) {
            int n = n0 + wc * 64 + fn * 16 + l15;
            float hbv = hp[b * H_ + n] + bias[n];
            float vvv = V[n];
#pragma unroll
            for (int fm = 0; fm < 4; ++fm) {
                f32x4 a = acc[fm][fn];
#pragma unroll
                for (int rg = 0; rg < 4; ++rg)
                    rowsum[fm][rg] += tanh_fast(a[rg] + hbv) * vvv;
            }
        }
    }

    __syncthreads();
    float* s_red = (float*)smem;
#pragma unroll
    for (int fm = 0; fm < 4; ++fm)
#pragma unroll
        for (int rg = 0; rg < 4; ++rg) {
            float v = rowsum[fm][rg];
            v += __shfl_xor(v, 1, 16);
            v += __shfl_xor(v, 2, 16);
            v += __shfl_xor(v, 4, 16);
            v += __shfl_xor(v, 8, 16);
            if (l15 == 0)
                s_red[wc * 128 + wr * 64 + fm * 16 + lhi * 4 + rg] = v;
        }
    __syncthreads();
    if (tid < 128) {
        int m = m0 + tid;
        float sc = s_red[tid] + s_red[128 + tid];
        scores_out[m] = (mask[m] == 1) ? sc : NEGV;
    }
#undef STAGE_LOAD
#undef STAGE_WRITE
}

__global__ __launch_bounds__(256) void k_softmax(const float* __restrict__ scores,
                                                 float* __restrict__ weights) {
    __shared__ float red[8];
    int b = blockIdx.x;
    int tid = threadIdx.x;
    const float* srow = scores + b * S_;
    float vals[8];
    float mx = -INFINITY;
#pragma unroll
    for (int i = 0; i < 8; ++i) {
        vals[i] = srow[tid + i * 256];
        mx = fmaxf(mx, vals[i]);
    }
    for (int off = 32; off; off >>= 1) mx = fmaxf(mx, __shfl_xor(mx, off, 64));
    int wave = tid >> 6;
    if ((tid & 63) == 0) red[wave] = mx;
    __syncthreads();
    mx = fmaxf(fmaxf(red[0], red[1]), fmaxf(red[2], red[3]));
    float sum = 0.f;
#pragma unroll
    for (int i = 0; i < 8; ++i) {
        vals[i] = expf(vals[i] - mx);
        sum += vals[i];
    }
    for (int off = 32; off; off >>= 1) sum += __shfl_xor(sum, off, 64);
    if ((tid & 63) == 0) red[4 + wave] = sum;
    __syncthreads();
    sum = red[4] + red[5] + red[6] + red[7];
    float inv = 1.f / sum;
#pragma unroll
    for (int i = 0; i < 8; ++i)
        weights[b * S_ + tid + i * 256] = vals[i] * inv;
}

extern "C" void kernel_launch(void* const* d_in, const int* in_sizes, int n_in,
                              void* d_out, int out_size, void* d_ws, size_t ws_size,
                              hipStream_t stream) {
    const float* ls   = (const float*)d_in[0];
    const float* enc  = (const float*)d_in[1];
    const int*   mask = (const int*)d_in[2];
    const float* W    = (const float*)d_in[3];
    const float* bias = (const float*)d_in[4];
    const float* V    = (const float*)d_in[5];

    float* out     = (float*)d_out;
    float* ctx     = out;
    float* weights = out + 32768;
    float* scores  = out + 98304;

    // fast path: Wf16(2MB) hp(128KB) spart(1MB) part(2MB) = ~5.3MB
    const size_t need = 2097152ull + 131072ull + 1048576ull + 2097152ull;

    if (ws_size >= need) {
        unsigned short* Wf16 = (unsigned short*)d_ws;         // 1Mi halves
        float* hp    = (float*)(Wf16 + 1048576);
        float* spart = hp + 32768;              // 4 * 65536 floats
        float* part  = spart + 262144;          // 512 * 1024 floats

        hipFuncSetAttribute((const void*)k_scores_m128,
                            hipFuncAttributeMaxDynamicSharedMemorySize, 98304);

        k_W_f16<<<512, 256, 0, stream>>>(W, Wf16);
        k_hpart<<<128, 256, 0, stream>>>(ls, W, hp);
        k_scores_m128<<<2048, 512, 98304, stream>>>(enc, Wf16, hp, bias, V, spart);
        k_softmax_fold<<<32, 256, 0, stream>>>(spart, mask, scores, weights);
        k_ctx_partial_f32<<<512, 256, 0, stream>>>(weights, enc, part);
        k_ctx_reduce<<<128, 256, 0, stream>>>(part, ctx);
    } else {
        unsigned short* Whi = (unsigned short*)d_ws;
        unsigned short* Wlo = Whi + 1048576;
        float* hp   = (float*)(Wlo + 1048576);
        float* part = hp + 32768;

        k_splitW_lin<<<512, 256, 0, stream>>>(W, Whi, Wlo);
        k_hpart<<<128, 256, 0, stream>>>(ls, W, hp);
        k_scores_mfma_fb<<<512, 256, 0, stream>>>(enc, Whi, Wlo, hp, bias, V, mask, scores);
        k_softmax<<<32, 256, 0, stream>>>(scores, weights);
        k_ctx_partial_f32<<<512, 256, 0, stream>>>(weights, enc, part);
        k_ctx_reduce<<<128, 256, 0, stream>>>(part, ctx);
    }
}

// Round 19
// 253.191 us; speedup vs baseline: 1.1379x; 1.1379x over previous
//
#include <hip/hip_runtime.h>
#include <math.h>
#include <stdint.h>

#define B_ 32
#define S_ 2048
#define D_ 1024
#define H_ 1024
#define NEGV -1000000000000.0f

typedef __attribute__((ext_vector_type(8))) short bf16x8;
typedef __attribute__((ext_vector_type(8))) _Float16 f16x8;
typedef __attribute__((ext_vector_type(4))) float f32x4;

static __device__ __forceinline__ unsigned short f2bf(float x) {
    union { float f; unsigned u; } v; v.f = x;
    unsigned r = v.u + 0x7FFF + ((v.u >> 16) & 1);
    return (unsigned short)(r >> 16);
}
static __device__ __forceinline__ float bf2f(unsigned short h) {
    union { float f; unsigned u; } v; v.u = ((unsigned)h) << 16; return v.f;
}
static __device__ __forceinline__ unsigned short f2h(float x) {
    _Float16 h = (_Float16)x; unsigned short u;
    __builtin_memcpy(&u, &h, 2); return u;
}
static __device__ __forceinline__ float h2f(unsigned short u) {
    _Float16 h; __builtin_memcpy(&h, &u, 2); return (float)h;
}
static __device__ __forceinline__ float tanh_fast(float x) {
    float e = __expf(2.f * x);
    return 1.f - 2.f / (e + 1.f);
}
static __device__ __forceinline__ void gl_lds16(unsigned short* lds, const unsigned short* g) {
    __builtin_amdgcn_global_load_lds(
        (const __attribute__((address_space(1))) unsigned int*)(const void*)g,
        (__attribute__((address_space(3))) unsigned int*)(void*)lds,
        16, 0, 0);
}

// ---------- We = W[:, D:] -> single fp16 plane, 8-CHUNK-SWIZZLED storage ----------
// within each 64-elem K-group: stored chunk c' = c ^ (row & 7)  (chunk = 8 elems = 16B)
__global__ __launch_bounds__(256) void k_W_f16(const float* __restrict__ W,
                                               unsigned short* __restrict__ out) {
    int idx = blockIdx.x * 256 + threadIdx.x;   // 131072 chunks
    int h = idx >> 7, kc = idx & 127;
    const float* src = W + (size_t)h * (2 * D_) + D_ + kc * 8;
    float4 a = *(const float4*)src;
    float4 c4 = *(const float4*)(src + 4);
    float v[8] = {a.x, a.y, a.z, a.w, c4.x, c4.y, c4.z, c4.w};
    unsigned short t[8];
#pragma unroll
    for (int j = 0; j < 8; ++j) t[j] = f2h(v[j]);
    uint4 w;
    w.x = t[0] | ((unsigned)t[1] << 16); w.y = t[2] | ((unsigned)t[3] << 16);
    w.z = t[4] | ((unsigned)t[5] << 16); w.w = t[6] | ((unsigned)t[7] << 16);
    int g = kc >> 3, cc = kc & 7;
    int dst = g * 64 + ((cc ^ (h & 7)) << 3);
    *(uint4*)(out + (size_t)h * D_ + dst) = w;
}

// ---------- h_part (fp32, exact) ----------
__global__ __launch_bounds__(256) void k_hpart(const float* __restrict__ ls,
                                               const float* __restrict__ W,
                                               float* __restrict__ hp) {
    int bh = blockIdx.x * 256 + threadIdx.x;
    int b = bh >> 10, h = bh & 1023;
    const float* lsr = ls + b * D_;
    const float* wr  = W + (size_t)h * (2 * D_);
    float acc = 0.f;
#pragma unroll 4
    for (int d = 0; d < D_; d += 4) {
        float4 a = *(const float4*)(lsr + d);
        float4 w = *(const float4*)(wr + d);
        acc += a.x * w.x + a.y * w.y + a.z * w.z + a.w * w.w;
    }
    hp[bh] = acc;
}

// ---------- main GEMM: BM=128, BN=256, BK=64, single-buffered 48KB, 4 waves/SIMD ----------
// Occupancy gambit: unified VGPR+AGPR budget must be <=128/wave for 4 waves/SIMD
// (r16-r18 evidence: acc AGPRs count against the budget; all prior variants were
// 144-236 total -> stuck at 2 waves/SIMD / 23% occupancy). Here: acc=64 (wave
// tile 64x64) + lean arch regs (no issue-early; A staged in 2 transient passes
// of 8 floats). LDS 48KB -> 2 blocks/CU (96KB). TLP (16 waves/CU) hides HBM
// latency and absorbs barrier drains across blocks.
// Schedule/iter: sync ; WRITE_A+STAGE_B(t) ; sync ; compute(t)
__global__ __launch_bounds__(512, 4) void k_scores_occ(
    const float* __restrict__ enc,
    const unsigned short* __restrict__ Wf16,
    const float* __restrict__ hp, const float* __restrict__ bias,
    const float* __restrict__ V, float* __restrict__ spart)
{
    extern __shared__ unsigned short smem[];     // 49152 B
    unsigned short* smemA = smem;                // 8192 shorts = 128x64 f16
    unsigned short* smemB = smem + 8192;         // 16384 shorts = 256x64 f16

    const int tid  = threadIdx.x;
    const int lane = tid & 63, wid = tid >> 6;
    const int wm = wid >> 2, wn = wid & 3;       // 2 x 4 waves, wave tile 64x64
    const int l15 = lane & 15, lhi = lane >> 4;

    // XCD-bijective block swizzle (nwg = 2048, 256 per XCD)
    const int bid  = blockIdx.x;
    const int wgid = (bid & 7) * 256 + (bid >> 3);
    const int mt = wgid >> 2, nt = wgid & 3;
    const int m0 = mt * 128;
    const int nt256 = nt * 256;
    const int b = m0 >> 11;

    // B staging (r17 geometry): wave covers rows [wid*32, wid*32+32)
    const size_t boff = (size_t)(nt256 + wid * 16 + (lane >> 3)) * D_ + (lane & 7) * 8;
    const int ldsb = wid * 1024;

    f32x4 acc[4][4];
#pragma unroll
    for (int i = 0; i < 4; ++i)
#pragma unroll
        for (int j = 0; j < 4; ++j)
            acc[i][j] = (f32x4){0.f, 0.f, 0.f, 0.f};

    const int swz = l15 & 7;

// A staging: 1024 pieces (128 rows x 8 chunks); thread does p = tid, tid+512.
// Transient regs only (~10): load 8 floats, convert, write 16B, twice.
#define STAGE_A(KOFS) do {                                                          \
    _Pragma("unroll")                                                               \
    for (int s_ = 0; s_ < 2; ++s_) {                                                \
        int p_ = tid + s_ * 512;                                                    \
        int row_ = p_ >> 3, pc_ = p_ & 7;                                           \
        const float* ap_ = enc + (size_t)(m0 + row_) * D_ + (KOFS) + pc_ * 8;       \
        float4 x0_ = *(const float4*)ap_;                                           \
        float4 x1_ = *(const float4*)(ap_ + 4);                                     \
        float v_[8] = {x0_.x, x0_.y, x0_.z, x0_.w, x1_.x, x1_.y, x1_.z, x1_.w};     \
        unsigned short t_[8];                                                       \
        _Pragma("unroll")                                                           \
        for (int j_ = 0; j_ < 8; ++j_) t_[j_] = f2h(v_[j_]);                        \
        uint4 w_;                                                                   \
        w_.x = t_[0] | ((unsigned)t_[1] << 16); w_.y = t_[2] | ((unsigned)t_[3] << 16); \
        w_.z = t_[4] | ((unsigned)t_[5] << 16); w_.w = t_[6] | ((unsigned)t_[7] << 16); \
        *(uint4*)&smemA[row_ * 64 + ((pc_ ^ (row_ & 7)) << 3)] = w_;                \
    }                                                                               \
} while (0)

#define STAGE_B(KOFS) do {                                                          \
    unsigned short* d0_ = &smemB[ldsb];                                             \
    unsigned short* d1_ = &smemB[8192 + ldsb];                                      \
    const unsigned short* s0_ = Wf16 + boff + (KOFS);                               \
    const unsigned short* s1_ = Wf16 + boff + 131072 + (KOFS);                      \
    gl_lds16(d0_, s0_);                                                             \
    gl_lds16(d0_ + 512, s0_ + 8192);                                                \
    gl_lds16(d1_, s1_);                                                             \
    gl_lds16(d1_ + 512, s1_ + 8192);                                                \
} while (0)

#define LDA(AR, KS) do {                                                            \
    _Pragma("unroll")                                                               \
    for (int fi_ = 0; fi_ < 4; ++fi_) {                                             \
        int row_ = wm * 64 + fi_ * 16 + l15;                                        \
        int ch_  = ((KS) * 4 + lhi) ^ swz;                                          \
        AR[fi_] = *(const f16x8*)&smemA[row_ * 64 + ch_ * 8];                       \
    }                                                                               \
} while (0)
#define LDB(BR, KS) do {                                                            \
    _Pragma("unroll")                                                               \
    for (int fi_ = 0; fi_ < 4; ++fi_) {                                             \
        int row_ = wn * 64 + fi_ * 16 + l15;                                        \
        int ch_  = ((KS) * 4 + lhi) ^ swz;                                          \
        BR[fi_] = *(const f16x8*)&smemB[row_ * 64 + ch_ * 8];                       \
    }                                                                               \
} while (0)
#define MFMA16(AR, BR) do {                                                         \
    _Pragma("unroll")                                                               \
    for (int fi_ = 0; fi_ < 4; ++fi_)                                               \
    _Pragma("unroll")                                                               \
        for (int fj_ = 0; fj_ < 4; ++fj_)                                           \
            acc[fi_][fj_] = __builtin_amdgcn_mfma_f32_16x16x32_f16(                 \
                AR[fi_], BR[fj_], acc[fi_][fj_], 0, 0, 0);                          \
} while (0)

    f16x8 a[4], bk[4];
#pragma unroll 1
    for (int t = 0; t < 16; ++t) {
        const int kofs = t * 64;

        STAGE_B(kofs);                    // 4 gl_lds (async)
        STAGE_A(kofs);                    // 2x {load8, cvt, ds_write}; transient regs
        __syncthreads();                  // vmcnt(0)+lgkmcnt(0)+barrier: tile visible

#pragma unroll
        for (int ks = 0; ks < 2; ++ks) {
            LDB(bk, ks);
            LDA(a, ks);
            MFMA16(a, bk);
        }

        __syncthreads();                  // reads done -> LDS reusable next iter
    }

    // ---- epilogue: tanh + V-weighted reduce
    float hb[4], vv[4];
#pragma unroll
    for (int fn = 0; fn < 4; ++fn) {
        int h = nt256 + wn * 64 + fn * 16 + l15;
        hb[fn] = hp[b * H_ + h] + bias[h];
        vv[fn] = V[h];
    }
    float* s_red = (float*)smem;          // 512 floats
#pragma unroll
    for (int fm = 0; fm < 4; ++fm)
#pragma unroll
        for (int rg = 0; rg < 4; ++rg) {
            float rs = 0.f;
#pragma unroll
            for (int fn = 0; fn < 4; ++fn)
                rs += tanh_fast(acc[fm][fn][rg] + hb[fn]) * vv[fn];
            rs += __shfl_xor(rs, 1, 16);
            rs += __shfl_xor(rs, 2, 16);
            rs += __shfl_xor(rs, 4, 16);
            rs += __shfl_xor(rs, 8, 16);
            if (l15 == 0)
                s_red[wn * 128 + wm * 64 + fm * 16 + lhi * 4 + rg] = rs;
        }
    __syncthreads();
    if (tid < 128) {
        float v = s_red[tid] + s_red[128 + tid] + s_red[256 + tid] + s_red[384 + tid];
        spart[(size_t)nt * 65536 + m0 + tid] = v;
    }
#undef STAGE_A
#undef STAGE_B
#undef LDA
#undef LDB
#undef MFMA16
}

// ---------- fold nt-partials + mask + softmax ----------
__global__ __launch_bounds__(256) void k_softmax_fold(const float* __restrict__ spart,
                                                      const int* __restrict__ mask,
                                                      float* __restrict__ scores_out,
                                                      float* __restrict__ weights) {
    __shared__ float red[8];
    int b = blockIdx.x, tid = threadIdx.x;
    float vals[8];
    float mx = -INFINITY;
#pragma unroll
    for (int i = 0; i < 8; ++i) {
        int m = b * S_ + tid + i * 256;
        float s = spart[m] + spart[65536 + m] + spart[131072 + m] + spart[196608 + m];
        s = (mask[m] == 1) ? s : NEGV;
        scores_out[m] = s;
        vals[i] = s;
        mx = fmaxf(mx, s);
    }
    for (int off = 32; off; off >>= 1) mx = fmaxf(mx, __shfl_xor(mx, off, 64));
    int wave = tid >> 6;
    if ((tid & 63) == 0) red[wave] = mx;
    __syncthreads();
    mx = fmaxf(fmaxf(red[0], red[1]), fmaxf(red[2], red[3]));
    float sum = 0.f;
#pragma unroll
    for (int i = 0; i < 8; ++i) {
        vals[i] = expf(vals[i] - mx);
        sum += vals[i];
    }
    for (int off = 32; off; off >>= 1) sum += __shfl_xor(sum, off, 64);
    if ((tid & 63) == 0) red[4 + wave] = sum;
    __syncthreads();
    sum = red[4] + red[5] + red[6] + red[7];
    float inv = 1.f / sum;
#pragma unroll
    for (int i = 0; i < 8; ++i)
        weights[b * S_ + tid + i * 256] = vals[i] * inv;
}

// ---------- context partials (fp32 enc, skip zero weights) ----------
__global__ __launch_bounds__(256) void k_ctx_partial_f32(const float* __restrict__ weights,
                                                         const float* __restrict__ enc,
                                                         float* __restrict__ part) {
    int b = blockIdx.x >> 4;
    int chunk = blockIdx.x & 15;
    int tid = threadIdx.x;
    int d0 = tid * 4;
    float4 acc = {0.f, 0.f, 0.f, 0.f};
    int s0 = chunk * 128;
    const float* wrow = weights + b * S_;
    for (int s = s0; s < s0 + 128; ++s) {
        float w = wrow[s];
        if (w != 0.f) {
            float4 e = *(const float4*)(enc + (size_t)(b * S_ + s) * D_ + d0);
            acc.x += w * e.x; acc.y += w * e.y; acc.z += w * e.z; acc.w += w * e.w;
        }
    }
    *(float4*)(part + (size_t)blockIdx.x * D_ + d0) = acc;
}

__global__ __launch_bounds__(256) void k_ctx_reduce(const float* __restrict__ part,
                                                    float* __restrict__ ctx) {
    int bd = blockIdx.x * 256 + threadIdx.x;
    int b = bd >> 10, d = bd & 1023;
    float acc = 0.f;
#pragma unroll
    for (int c = 0; c < 16; ++c)
        acc += part[(size_t)(b * 16 + c) * D_ + d];
    ctx[bd] = acc;
}

// ================== fallback path (tiny ws): linear bf16 split + round-2 kernel ==================
__global__ __launch_bounds__(256) void k_splitW_lin(const float* __restrict__ W,
                                                    unsigned short* __restrict__ hi,
                                                    unsigned short* __restrict__ lo) {
    int idx = blockIdx.x * 256 + threadIdx.x;
    int h = idx >> 7, kc = idx & 127;
    const float* src = W + (size_t)h * (2 * D_) + D_ + kc * 8;
    float4 a = *(const float4*)src;
    float4 c = *(const float4*)(src + 4);
    float v[8] = {a.x, a.y, a.z, a.w, c.x, c.y, c.z, c.w};
    unsigned short th[8], tl[8];
#pragma unroll
    for (int j = 0; j < 8; ++j) {
        th[j] = f2bf(v[j]);
        tl[j] = f2bf(v[j] - bf2f(th[j]));
    }
    uint4 hw, lw;
    hw.x = th[0] | ((unsigned)th[1] << 16); hw.y = th[2] | ((unsigned)th[3] << 16);
    hw.z = th[4] | ((unsigned)th[5] << 16); hw.w = th[6] | ((unsigned)th[7] << 16);
    lw.x = tl[0] | ((unsigned)tl[1] << 16); lw.y = tl[2] | ((unsigned)tl[3] << 16);
    lw.z = tl[4] | ((unsigned)tl[5] << 16); lw.w = tl[6] | ((unsigned)tl[7] << 16);
    *(uint4*)(hi + (size_t)h * D_ + kc * 8) = hw;
    *(uint4*)(lo + (size_t)h * D_ + kc * 8) = lw;
}

__global__ __launch_bounds__(256, 2) void k_scores_mfma_fb(
    const float* __restrict__ enc,
    const unsigned short* __restrict__ Whi,
    const unsigned short* __restrict__ Wlo,
    const float* __restrict__ hp,
    const float* __restrict__ bias,
    const float* __restrict__ V,
    const int* __restrict__ mask,
    float* __restrict__ scores_out)
{
    __shared__ __align__(16) unsigned short smem[4 * 8192];
    unsigned short* sAhi = smem;
    unsigned short* sAlo = smem + 8192;
    unsigned short* sBhi = smem + 16384;
    unsigned short* sBlo = smem + 24576;

    const int tid  = threadIdx.x;
    const int lane = tid & 63, wid = tid >> 6;
    const int wr = wid >> 1, wc = wid & 1;
    const int l15 = lane & 15, lhi = lane >> 4;
    const int m0 = blockIdx.x * 128;
    const int b  = m0 >> 11;

    float rowsum[4][4] = {};
    float4 pa[8];
    uint4  pbh[4], pbl[4];

#define STAGE_LOAD(NB, KB) do {                                            \
    _Pragma("unroll")                                                      \
    for (int i_ = 0; i_ < 4; ++i_) {                                       \
        int c_ = tid + i_ * 256;                                           \
        int r_ = c_ >> 3, kc_ = c_ & 7;                                    \
        const float* ap_ = enc + (size_t)(m0 + r_) * D_ + (KB) * 64 + kc_ * 8; \
        pa[2 * i_]     = *(const float4*)ap_;                              \
        pa[2 * i_ + 1] = *(const float4*)(ap_ + 4);                        \
        size_t bo_ = (size_t)((NB) * 128 + r_) * D_ + (KB) * 64 + kc_ * 8; \
        pbh[i_] = *(const uint4*)(Whi + bo_);                              \
        pbl[i_] = *(const uint4*)(Wlo + bo_);                              \
    }                                                                      \
} while (0)

#define STAGE_WRITE() do {                                                 \
    _Pragma("unroll")                                                      \
    for (int i_ = 0; i_ < 4; ++i_) {                                       \
        int c_ = tid + i_ * 256;                                           \
        int sc_ = c_ ^ ((c_ >> 3) & 7);                                    \
        float vv_[8] = {pa[2*i_].x, pa[2*i_].y, pa[2*i_].z, pa[2*i_].w,    \
                        pa[2*i_+1].x, pa[2*i_+1].y, pa[2*i_+1].z, pa[2*i_+1].w}; \
        unsigned short th_[8], tl_[8];                                     \
        _Pragma("unroll")                                                  \
        for (int j_ = 0; j_ < 8; ++j_) {                                   \
            th_[j_] = f2bf(vv_[j_]);                                       \
            tl_[j_] = f2bf(vv_[j_] - bf2f(th_[j_]));                       \
        }                                                                  \
        uint4 hw_, lw_;                                                    \
        hw_.x = th_[0] | ((unsigned)th_[1] << 16); hw_.y = th_[2] | ((unsigned)th_[3] << 16); \
        hw_.z = th_[4] | ((unsigned)th_[5] << 16); hw_.w = th_[6] | ((unsigned)th_[7] << 16); \
        lw_.x = tl_[0] | ((unsigned)tl_[1] << 16); lw_.y = tl_[2] | ((unsigned)tl_[3] << 16); \
        lw_.z = tl_[4] | ((unsigned)tl_[5] << 16); lw_.w = tl_[6] | ((unsigned)tl_[7] << 16); \
        *(uint4*)&sAhi[sc_ * 8] = hw_;                                     \
        *(uint4*)&sAlo[sc_ * 8] = lw_;                                     \
        *(uint4*)&sBhi[sc_ * 8] = pbh[i_];                                 \
        *(uint4*)&sBlo[sc_ * 8] = pbl[i_];                                 \
    }                                                                      \
} while (0)

    STAGE_LOAD(0, 0);

    for (int nb = 0; nb < 8; ++nb) {
        f32x4 acc[4][4];
#pragma unroll
        for (int i = 0; i < 4; ++i)
#pragma unroll
            for (int j = 0; j < 4; ++j)
                acc[i][j] = (f32x4){0.f, 0.f, 0.f, 0.f};

        for (int kb = 0; kb < 16; ++kb) {
            __syncthreads();
            STAGE_WRITE();
            __syncthreads();
            int nkb = kb + 1, nnb = nb;
            if (nkb == 16) { nkb = 0; nnb = nb + 1; }
            if (nnb < 8) STAGE_LOAD(nnb, nkb);

#pragma unroll
            for (int ks = 0; ks < 2; ++ks) {
                bf16x8 bh[4], bl[4];
#pragma unroll
                for (int fn = 0; fn < 4; ++fn) {
                    int rB = wc * 64 + fn * 16 + l15;
                    int ch = (rB * 8 + ks * 4 + lhi) ^ (rB & 7);
                    bh[fn] = *(const bf16x8*)&sBhi[ch * 8];
                    bl[fn] = *(const bf16x8*)&sBlo[ch * 8];
                }
#pragma unroll
                for (int fm = 0; fm < 4; ++fm) {
                    int rA = wr * 64 + fm * 16 + l15;
                    int ch = (rA * 8 + ks * 4 + lhi) ^ (rA & 7);
                    bf16x8 ah = *(const bf16x8*)&sAhi[ch * 8];
                    bf16x8 al = *(const bf16x8*)&sAlo[ch * 8];
#pragma unroll
                    for (int fn = 0; fn < 4; ++fn) {
                        acc[fm][fn] = __builtin_amdgcn_mfma_f32_16x16x32_bf16(ah, bh[fn], acc[fm][fn], 0, 0, 0);
                        acc[fm][fn] = __builtin_amdgcn_mfma_f32_16x16x32_bf16(ah, bl[fn], acc[fm][fn], 0, 0, 0);
                        acc[fm][fn] = __builtin_amdgcn_mfma_f32_16x16x32_bf16(al, bh[fn], acc[fm][fn], 0, 0, 0);
                    }
                }
            }
        }

        int n0 = nb * 128;
#pragma unroll
        for (int fn = 0; fn < 4; ++fn) {
            int n = n0 + wc * 64 + fn * 16 + l15;
            float hbv = hp[b * H_ + n] + bias[n];
            float vvv = V[n];
#pragma unroll
            for (int fm = 0; fm < 4; ++fm) {
                f32x4 a = acc[fm][fn];
#pragma unroll
                for (int rg = 0; rg < 4; ++rg)
                    rowsum[fm][rg] += tanh_fast(a[rg] + hbv) * vvv;
            }
        }
    }

    __syncthreads();
    float* s_red = (float*)smem;
#pragma unroll
    for (int fm = 0; fm < 4; ++fm)
#pragma unroll
        for (int rg = 0; rg < 4; ++rg) {
            float v = rowsum[fm][rg];
            v += __shfl_xor(v, 1, 16);
            v += __shfl_xor(v, 2, 16);
            v += __shfl_xor(v, 4, 16);
            v += __shfl_xor(v, 8, 16);
            if (l15 == 0)
                s_red[wc * 128 + wr * 64 + fm * 16 + lhi * 4 + rg] = v;
        }
    __syncthreads();
    if (tid < 128) {
        int m = m0 + tid;
        float sc = s_red[tid] + s_red[128 + tid];
        scores_out[m] = (mask[m] == 1) ? sc : NEGV;
    }
#undef STAGE_LOAD
#undef STAGE_WRITE
}

__global__ __launch_bounds__(256) void k_softmax(const float* __restrict__ scores,
                                                 float* __restrict__ weights) {
    __shared__ float red[8];
    int b = blockIdx.x;
    int tid = threadIdx.x;
    const float* srow = scores + b * S_;
    float vals[8];
    float mx = -INFINITY;
#pragma unroll
    for (int i = 0; i < 8; ++i) {
        vals[i] = srow[tid + i * 256];
        mx = fmaxf(mx, vals[i]);
    }
    for (int off = 32; off; off >>= 1) mx = fmaxf(mx, __shfl_xor(mx, off, 64));
    int wave = tid >> 6;
    if ((tid & 63) == 0) red[wave] = mx;
    __syncthreads();
    mx = fmaxf(fmaxf(red[0], red[1]), fmaxf(red[2], red[3]));
    float sum = 0.f;
#pragma unroll
    for (int i = 0; i < 8; ++i) {
        vals[i] = expf(vals[i] - mx);
        sum += vals[i];
    }
    for (int off = 32; off; off >>= 1) sum += __shfl_xor(sum, off, 64);
    if ((tid & 63) == 0) red[4 + wave] = sum;
    __syncthreads();
    sum = red[4] + red[5] + red[6] + red[7];
    float inv = 1.f / sum;
#pragma unroll
    for (int i = 0; i < 8; ++i)
        weights[b * S_ + tid + i * 256] = vals[i] * inv;
}

extern "C" void kernel_launch(void* const* d_in, const int* in_sizes, int n_in,
                              void* d_out, int out_size, void* d_ws, size_t ws_size,
                              hipStream_t stream) {
    const float* ls   = (const float*)d_in[0];
    const float* enc  = (const float*)d_in[1];
    const int*   mask = (const int*)d_in[2];
    const float* W    = (const float*)d_in[3];
    const float* bias = (const float*)d_in[4];
    const float* V    = (const float*)d_in[5];

    float* out     = (float*)d_out;
    float* ctx     = out;
    float* weights = out + 32768;
    float* scores  = out + 98304;

    // fast path: Wf16(2MB) hp(128KB) spart(1MB) part(2MB) = ~5.3MB
    const size_t need = 2097152ull + 131072ull + 1048576ull + 2097152ull;

    if (ws_size >= need) {
        unsigned short* Wf16 = (unsigned short*)d_ws;         // 1Mi halves
        float* hp    = (float*)(Wf16 + 1048576);
        float* spart = hp + 32768;              // 4 * 65536 floats
        float* part  = spart + 262144;          // 512 * 1024 floats

        hipFuncSetAttribute((const void*)k_scores_occ,
                            hipFuncAttributeMaxDynamicSharedMemorySize, 49152);

        k_W_f16<<<512, 256, 0, stream>>>(W, Wf16);
        k_hpart<<<128, 256, 0, stream>>>(ls, W, hp);
        k_scores_occ<<<2048, 512, 49152, stream>>>(enc, Wf16, hp, bias, V, spart);
        k_softmax_fold<<<32, 256, 0, stream>>>(spart, mask, scores, weights);
        k_ctx_partial_f32<<<512, 256, 0, stream>>>(weights, enc, part);
        k_ctx_reduce<<<128, 256, 0, stream>>>(part, ctx);
    } else {
        unsigned short* Whi = (unsigned short*)d_ws;
        unsigned short* Wlo = Whi + 1048576;
        float* hp   = (float*)(Wlo + 1048576);
        float* part = hp + 32768;

        k_splitW_lin<<<512, 256, 0, stream>>>(W, Whi, Wlo);
        k_hpart<<<128, 256, 0, stream>>>(ls, W, hp);
        k_scores_mfma_fb<<<512, 256, 0, stream>>>(enc, Whi, Wlo, hp, bias, V, mask, scores);
        k_softmax<<<32, 256, 0, stream>>>(scores, weights);
        k_ctx_partial_f32<<<512, 256, 0, stream>>>(weights, enc, part);
        k_ctx_reduce<<<128, 256, 0, stream>>>(part, ctx);
    }
}

// Round 20
// 245.309 us; speedup vs baseline: 1.1744x; 1.0321x over previous
//
#include <hip/hip_runtime.h>
#include <math.h>
#include <stdint.h>

#define B_ 32
#define S_ 2048
#define D_ 1024
#define H_ 1024
#define NEGV -1000000000000.0f

typedef __attribute__((ext_vector_type(8))) short bf16x8;
typedef __attribute__((ext_vector_type(8))) _Float16 f16x8;
typedef __attribute__((ext_vector_type(4))) float f32x4;

static __device__ __forceinline__ unsigned short f2bf(float x) {
    union { float f; unsigned u; } v; v.f = x;
    unsigned r = v.u + 0x7FFF + ((v.u >> 16) & 1);
    return (unsigned short)(r >> 16);
}
static __device__ __forceinline__ float bf2f(unsigned short h) {
    union { float f; unsigned u; } v; v.u = ((unsigned)h) << 16; return v.f;
}
static __device__ __forceinline__ unsigned short f2h(float x) {
    _Float16 h = (_Float16)x; unsigned short u;
    __builtin_memcpy(&u, &h, 2); return u;
}
static __device__ __forceinline__ float h2f(unsigned short u) {
    _Float16 h; __builtin_memcpy(&h, &u, 2); return (float)h;
}
static __device__ __forceinline__ float tanh_fast(float x) {
    float e = __expf(2.f * x);
    return 1.f - 2.f / (e + 1.f);
}
static __device__ __forceinline__ void gl_lds16(unsigned short* lds, const unsigned short* g) {
    __builtin_amdgcn_global_load_lds(
        (const __attribute__((address_space(1))) unsigned int*)(const void*)g,
        (__attribute__((address_space(3))) unsigned int*)(void*)lds,
        16, 0, 0);
}

// ---------- fused prep: blocks 0..511 convert We -> fp16 (8-chunk-swizzled);
//            blocks 512..639 compute h_part (fp32, exact) ----------
__global__ __launch_bounds__(256) void k_prep(const float* __restrict__ W,
                                              const float* __restrict__ ls,
                                              unsigned short* __restrict__ out,
                                              float* __restrict__ hp) {
    if (blockIdx.x < 512) {
        int idx = blockIdx.x * 256 + threadIdx.x;   // 131072 chunks
        int h = idx >> 7, kc = idx & 127;
        const float* src = W + (size_t)h * (2 * D_) + D_ + kc * 8;
        float4 a = *(const float4*)src;
        float4 c4 = *(const float4*)(src + 4);
        float v[8] = {a.x, a.y, a.z, a.w, c4.x, c4.y, c4.z, c4.w};
        unsigned short t[8];
#pragma unroll
        for (int j = 0; j < 8; ++j) t[j] = f2h(v[j]);
        uint4 w;
        w.x = t[0] | ((unsigned)t[1] << 16); w.y = t[2] | ((unsigned)t[3] << 16);
        w.z = t[4] | ((unsigned)t[5] << 16); w.w = t[6] | ((unsigned)t[7] << 16);
        int g = kc >> 3, cc = kc & 7;
        int dst = g * 64 + ((cc ^ (h & 7)) << 3);
        *(uint4*)(out + (size_t)h * D_ + dst) = w;
    } else {
        int bh = (blockIdx.x - 512) * 256 + threadIdx.x;  // 32768
        int b = bh >> 10, h = bh & 1023;
        const float* lsr = ls + b * D_;
        const float* wr  = W + (size_t)h * (2 * D_);
        float acc = 0.f;
#pragma unroll 4
        for (int d = 0; d < D_; d += 4) {
            float4 a = *(const float4*)(lsr + d);
            float4 w = *(const float4*)(wr + d);
            acc += a.x * w.x + a.y * w.y + a.z * w.z + a.w * w.w;
        }
        hp[bh] = acc;
    }
}

// ---------- main GEMM: BM=128, BN=256, BK=64, single-buffered 48KB, 4 waves/SIMD ----------
// r19 kernel, byte-identical (best measured total: 253us, occ 43.6%, VGPR 56,
// no spill). Plateau evidence: r12/r15/r17/r18/r19 all pin MfmaUtil 24-26%
// regardless of occupancy/buffering -> bottleneck is the 2-sync-per-tile
// structure; counted-vmcnt restructures regressed twice (r5 race, r13 -19%).
// Schedule/iter: STAGE_B+STAGE_A(t) ; sync ; compute(t) ; sync
__global__ __launch_bounds__(512, 4) void k_scores_occ(
    const float* __restrict__ enc,
    const unsigned short* __restrict__ Wf16,
    const float* __restrict__ hp, const float* __restrict__ bias,
    const float* __restrict__ V, float* __restrict__ spart)
{
    extern __shared__ unsigned short smem[];     // 49152 B
    unsigned short* smemA = smem;                // 8192 shorts = 128x64 f16
    unsigned short* smemB = smem + 8192;         // 16384 shorts = 256x64 f16

    const int tid  = threadIdx.x;
    const int lane = tid & 63, wid = tid >> 6;
    const int wm = wid >> 2, wn = wid & 3;       // 2 x 4 waves, wave tile 64x64
    const int l15 = lane & 15, lhi = lane >> 4;

    // XCD-bijective block swizzle (nwg = 2048, 256 per XCD)
    const int bid  = blockIdx.x;
    const int wgid = (bid & 7) * 256 + (bid >> 3);
    const int mt = wgid >> 2, nt = wgid & 3;
    const int m0 = mt * 128;
    const int nt256 = nt * 256;
    const int b = m0 >> 11;

    const size_t boff = (size_t)(nt256 + wid * 16 + (lane >> 3)) * D_ + (lane & 7) * 8;
    const int ldsb = wid * 1024;

    f32x4 acc[4][4];
#pragma unroll
    for (int i = 0; i < 4; ++i)
#pragma unroll
        for (int j = 0; j < 4; ++j)
            acc[i][j] = (f32x4){0.f, 0.f, 0.f, 0.f};

    const int swz = l15 & 7;

#define STAGE_A(KOFS) do {                                                          \
    _Pragma("unroll")                                                               \
    for (int s_ = 0; s_ < 2; ++s_) {                                                \
        int p_ = tid + s_ * 512;                                                    \
        int row_ = p_ >> 3, pc_ = p_ & 7;                                           \
        const float* ap_ = enc + (size_t)(m0 + row_) * D_ + (KOFS) + pc_ * 8;       \
        float4 x0_ = *(const float4*)ap_;                                           \
        float4 x1_ = *(const float4*)(ap_ + 4);                                     \
        float v_[8] = {x0_.x, x0_.y, x0_.z, x0_.w, x1_.x, x1_.y, x1_.z, x1_.w};     \
        unsigned short t_[8];                                                       \
        _Pragma("unroll")                                                           \
        for (int j_ = 0; j_ < 8; ++j_) t_[j_] = f2h(v_[j_]);                        \
        uint4 w_;                                                                   \
        w_.x = t_[0] | ((unsigned)t_[1] << 16); w_.y = t_[2] | ((unsigned)t_[3] << 16); \
        w_.z = t_[4] | ((unsigned)t_[5] << 16); w_.w = t_[6] | ((unsigned)t_[7] << 16); \
        *(uint4*)&smemA[row_ * 64 + ((pc_ ^ (row_ & 7)) << 3)] = w_;                \
    }                                                                               \
} while (0)

#define STAGE_B(KOFS) do {                                                          \
    unsigned short* d0_ = &smemB[ldsb];                                             \
    unsigned short* d1_ = &smemB[8192 + ldsb];                                      \
    const unsigned short* s0_ = Wf16 + boff + (KOFS);                               \
    const unsigned short* s1_ = Wf16 + boff + 131072 + (KOFS);                      \
    gl_lds16(d0_, s0_);                                                             \
    gl_lds16(d0_ + 512, s0_ + 8192);                                                \
    gl_lds16(d1_, s1_);                                                             \
    gl_lds16(d1_ + 512, s1_ + 8192);                                                \
} while (0)

#define LDA(AR, KS) do {                                                            \
    _Pragma("unroll")                                                               \
    for (int fi_ = 0; fi_ < 4; ++fi_) {                                             \
        int row_ = wm * 64 + fi_ * 16 + l15;                                        \
        int ch_  = ((KS) * 4 + lhi) ^ swz;                                          \
        AR[fi_] = *(const f16x8*)&smemA[row_ * 64 + ch_ * 8];                       \
    }                                                                               \
} while (0)
#define LDB(BR, KS) do {                                                            \
    _Pragma("unroll")                                                               \
    for (int fi_ = 0; fi_ < 4; ++fi_) {                                             \
        int row_ = wn * 64 + fi_ * 16 + l15;                                        \
        int ch_  = ((KS) * 4 + lhi) ^ swz;                                          \
        BR[fi_] = *(const f16x8*)&smemB[row_ * 64 + ch_ * 8];                       \
    }                                                                               \
} while (0)
#define MFMA16(AR, BR) do {                                                         \
    _Pragma("unroll")                                                               \
    for (int fi_ = 0; fi_ < 4; ++fi_)                                               \
    _Pragma("unroll")                                                               \
        for (int fj_ = 0; fj_ < 4; ++fj_)                                           \
            acc[fi_][fj_] = __builtin_amdgcn_mfma_f32_16x16x32_f16(                 \
                AR[fi_], BR[fj_], acc[fi_][fj_], 0, 0, 0);                          \
} while (0)

    f16x8 a[4], bk[4];
#pragma unroll 1
    for (int t = 0; t < 16; ++t) {
        const int kofs = t * 64;

        STAGE_B(kofs);                    // 4 gl_lds (async)
        STAGE_A(kofs);                    // 2x {load8, cvt, ds_write}; transient regs
        __syncthreads();                  // vmcnt(0)+lgkmcnt(0)+barrier: tile visible

#pragma unroll
        for (int ks = 0; ks < 2; ++ks) {
            LDB(bk, ks);
            LDA(a, ks);
            MFMA16(a, bk);
        }

        __syncthreads();                  // reads done -> LDS reusable next iter
    }

    // ---- epilogue: tanh + V-weighted reduce
    float hb[4], vv[4];
#pragma unroll
    for (int fn = 0; fn < 4; ++fn) {
        int h = nt256 + wn * 64 + fn * 16 + l15;
        hb[fn] = hp[b * H_ + h] + bias[h];
        vv[fn] = V[h];
    }
    float* s_red = (float*)smem;          // 512 floats
#pragma unroll
    for (int fm = 0; fm < 4; ++fm)
#pragma unroll
        for (int rg = 0; rg < 4; ++rg) {
            float rs = 0.f;
#pragma unroll
            for (int fn = 0; fn < 4; ++fn)
                rs += tanh_fast(acc[fm][fn][rg] + hb[fn]) * vv[fn];
            rs += __shfl_xor(rs, 1, 16);
            rs += __shfl_xor(rs, 2, 16);
            rs += __shfl_xor(rs, 4, 16);
            rs += __shfl_xor(rs, 8, 16);
            if (l15 == 0)
                s_red[wn * 128 + wm * 64 + fm * 16 + lhi * 4 + rg] = rs;
        }
    __syncthreads();
    if (tid < 128) {
        float v = s_red[tid] + s_red[128 + tid] + s_red[256 + tid] + s_red[384 + tid];
        spart[(size_t)nt * 65536 + m0 + tid] = v;
    }
#undef STAGE_A
#undef STAGE_B
#undef LDA
#undef LDB
#undef MFMA16
}

// ---------- fold nt-partials + mask + softmax ----------
__global__ __launch_bounds__(256) void k_softmax_fold(const float* __restrict__ spart,
                                                      const int* __restrict__ mask,
                                                      float* __restrict__ scores_out,
                                                      float* __restrict__ weights) {
    __shared__ float red[8];
    int b = blockIdx.x, tid = threadIdx.x;
    float vals[8];
    float mx = -INFINITY;
#pragma unroll
    for (int i = 0; i < 8; ++i) {
        int m = b * S_ + tid + i * 256;
        float s = spart[m] + spart[65536 + m] + spart[131072 + m] + spart[196608 + m];
        s = (mask[m] == 1) ? s : NEGV;
        scores_out[m] = s;
        vals[i] = s;
        mx = fmaxf(mx, s);
    }
    for (int off = 32; off; off >>= 1) mx = fmaxf(mx, __shfl_xor(mx, off, 64));
    int wave = tid >> 6;
    if ((tid & 63) == 0) red[wave] = mx;
    __syncthreads();
    mx = fmaxf(fmaxf(red[0], red[1]), fmaxf(red[2], red[3]));
    float sum = 0.f;
#pragma unroll
    for (int i = 0; i < 8; ++i) {
        vals[i] = expf(vals[i] - mx);
        sum += vals[i];
    }
    for (int off = 32; off; off >>= 1) sum += __shfl_xor(sum, off, 64);
    if ((tid & 63) == 0) red[4 + wave] = sum;
    __syncthreads();
    sum = red[4] + red[5] + red[6] + red[7];
    float inv = 1.f / sum;
#pragma unroll
    for (int i = 0; i < 8; ++i)
        weights[b * S_ + tid + i * 256] = vals[i] * inv;
}

// ---------- context partials (fp32 enc, skip zero weights) ----------
__global__ __launch_bounds__(256) void k_ctx_partial_f32(const float* __restrict__ weights,
                                                         const float* __restrict__ enc,
                                                         float* __restrict__ part) {
    int b = blockIdx.x >> 4;
    int chunk = blockIdx.x & 15;
    int tid = threadIdx.x;
    int d0 = tid * 4;
    float4 acc = {0.f, 0.f, 0.f, 0.f};
    int s0 = chunk * 128;
    const float* wrow = weights + b * S_;
    for (int s = s0; s < s0 + 128; ++s) {
        float w = wrow[s];
        if (w != 0.f) {
            float4 e = *(const float4*)(enc + (size_t)(b * S_ + s) * D_ + d0);
            acc.x += w * e.x; acc.y += w * e.y; acc.z += w * e.z; acc.w += w * e.w;
        }
    }
    *(float4*)(part + (size_t)blockIdx.x * D_ + d0) = acc;
}

__global__ __launch_bounds__(256) void k_ctx_reduce(const float* __restrict__ part,
                                                    float* __restrict__ ctx) {
    int bd = blockIdx.x * 256 + threadIdx.x;
    int b = bd >> 10, d = bd & 1023;
    float acc = 0.f;
#pragma unroll
    for (int c = 0; c < 16; ++c)
        acc += part[(size_t)(b * 16 + c) * D_ + d];
    ctx[bd] = acc;
}

// ================== fallback path (tiny ws): linear bf16 split + round-2 kernel ==================
__global__ __launch_bounds__(256) void k_splitW_lin(const float* __restrict__ W,
                                                    unsigned short* __restrict__ hi,
                                                    unsigned short* __restrict__ lo) {
    int idx = blockIdx.x * 256 + threadIdx.x;
    int h = idx >> 7, kc = idx & 127;
    const float* src = W + (size_t)h * (2 * D_) + D_ + kc * 8;
    float4 a = *(const float4*)src;
    float4 c = *(const float4*)(src + 4);
    float v[8] = {a.x, a.y, a.z, a.w, c.x, c.y, c.z, c.w};
    unsigned short th[8], tl[8];
#pragma unroll
    for (int j = 0; j < 8; ++j) {
        th[j] = f2bf(v[j]);
        tl[j] = f2bf(v[j] - bf2f(th[j]));
    }
    uint4 hw, lw;
    hw.x = th[0] | ((unsigned)th[1] << 16); hw.y = th[2] | ((unsigned)th[3] << 16);
    hw.z = th[4] | ((unsigned)th[5] << 16); hw.w = th[6] | ((unsigned)th[7] << 16);
    lw.x = tl[0] | ((unsigned)tl[1] << 16); lw.y = tl[2] | ((unsigned)tl[3] << 16);
    lw.z = tl[4] | ((unsigned)tl[5] << 16); lw.w = tl[6] | ((unsigned)tl[7] << 16);
    *(uint4*)(hi + (size_t)h * D_ + kc * 8) = hw;
    *(uint4*)(lo + (size_t)h * D_ + kc * 8) = lw;
}

__global__ __launch_bounds__(256) void k_hpart_fb(const float* __restrict__ ls,
                                                  const float* __restrict__ W,
                                                  float* __restrict__ hp) {
    int bh = blockIdx.x * 256 + threadIdx.x;
    int b = bh >> 10, h = bh & 1023;
    const float* lsr = ls + b * D_;
    const float* wr  = W + (size_t)h * (2 * D_);
    float acc = 0.f;
#pragma unroll 4
    for (int d = 0; d < D_; d += 4) {
        float4 a = *(const float4*)(lsr + d);
        float4 w = *(const float4*)(wr + d);
        acc += a.x * w.x + a.y * w.y + a.z * w.z + a.w * w.w;
    }
    hp[bh] = acc;
}

__global__ __launch_bounds__(256, 2) void k_scores_mfma_fb(
    const float* __restrict__ enc,
    const unsigned short* __restrict__ Whi,
    const unsigned short* __restrict__ Wlo,
    const float* __restrict__ hp,
    const float* __restrict__ bias,
    const float* __restrict__ V,
    const int* __restrict__ mask,
    float* __restrict__ scores_out)
{
    __shared__ __align__(16) unsigned short smem[4 * 8192];
    unsigned short* sAhi = smem;
    unsigned short* sAlo = smem + 8192;
    unsigned short* sBhi = smem + 16384;
    unsigned short* sBlo = smem + 24576;

    const int tid  = threadIdx.x;
    const int lane = tid & 63, wid = tid >> 6;
    const int wr = wid >> 1, wc = wid & 1;
    const int l15 = lane & 15, lhi = lane >> 4;
    const int m0 = blockIdx.x * 128;
    const int b  = m0 >> 11;

    float rowsum[4][4] = {};
    float4 pa[8];
    uint4  pbh[4], pbl[4];

#define STAGE_LOAD(NB, KB) do {                                            \
    _Pragma("unroll")                                                      \
    for (int i_ = 0; i_ < 4; ++i_) {                                       \
        int c_ = tid + i_ * 256;                                           \
        int r_ = c_ >> 3, kc_ = c_ & 7;                                    \
        const float* ap_ = enc + (size_t)(m0 + r_) * D_ + (KB) * 64 + kc_ * 8; \
        pa[2 * i_]     = *(const float4*)ap_;                              \
        pa[2 * i_ + 1] = *(const float4*)(ap_ + 4);                        \
        size_t bo_ = (size_t)((NB) * 128 + r_) * D_ + (KB) * 64 + kc_ * 8; \
        pbh[i_] = *(const uint4*)(Whi + bo_);                              \
        pbl[i_] = *(const uint4*)(Wlo + bo_);                              \
    }                                                                      \
} while (0)

#define STAGE_WRITE() do {                                                 \
    _Pragma("unroll")                                                      \
    for (int i_ = 0; i_ < 4; ++i_) {                                       \
        int c_ = tid + i_ * 256;                                           \
        int sc_ = c_ ^ ((c_ >> 3) & 7);                                    \
        float vv_[8] = {pa[2*i_].x, pa[2*i_].y, pa[2*i_].z, pa[2*i_].w,    \
                        pa[2*i_+1].x, pa[2*i_+1].y, pa[2*i_+1].z, pa[2*i_+1].w}; \
        unsigned short th_[8], tl_[8];                                     \
        _Pragma("unroll")                                                  \
        for (int j_ = 0; j_ < 8; ++j_) {                                   \
            th_[j_] = f2bf(vv_[j_]);                                       \
            tl_[j_] = f2bf(vv_[j_] - bf2f(th_[j_]));                       \
        }                                                                  \
        uint4 hw_, lw_;                                                    \
        hw_.x = th_[0] | ((unsigned)th_[1] << 16); hw_.y = th_[2] | ((unsigned)th_[3] << 16); \
        hw_.z = th_[4] | ((unsigned)th_[5] << 16); hw_.w = th_[6] | ((unsigned)th_[7] << 16); \
        lw_.x = tl_[0] | ((unsigned)tl_[1] << 16); lw_.y = tl_[2] | ((unsigned)tl_[3] << 16); \
        lw_.z = tl_[4] | ((unsigned)tl_[5] << 16); lw_.w = tl_[6] | ((unsigned)tl_[7] << 16); \
        *(uint4*)&sAhi[sc_ * 8] = hw_;                                     \
        *(uint4*)&sAlo[sc_ * 8] = lw_;                                     \
        *(uint4*)&sBhi[sc_ * 8] = pbh[i_];                                 \
        *(uint4*)&sBlo[sc_ * 8] = pbl[i_];                                 \
    }                                                                      \
} while (0)

    STAGE_LOAD(0, 0);

    for (int nb = 0; nb < 8; ++nb) {
        f32x4 acc[4][4];
#pragma unroll
        for (int i = 0; i < 4; ++i)
#pragma unroll
            for (int j = 0; j < 4; ++j)
                acc[i][j] = (f32x4){0.f, 0.f, 0.f, 0.f};

        for (int kb = 0; kb < 16; ++kb) {
            __syncthreads();
            STAGE_WRITE();
            __syncthreads();
            int nkb = kb + 1, nnb = nb;
            if (nkb == 16) { nkb = 0; nnb = nb + 1; }
            if (nnb < 8) STAGE_LOAD(nnb, nkb);

#pragma unroll
            for (int ks = 0; ks < 2; ++ks) {
                bf16x8 bh[4], bl[4];
#pragma unroll
                for (int fn = 0; fn < 4; ++fn) {
                    int rB = wc * 64 + fn * 16 + l15;
                    int ch = (rB * 8 + ks * 4 + lhi) ^ (rB & 7);
                    bh[fn] = *(const bf16x8*)&sBhi[ch * 8];
                    bl[fn] = *(const bf16x8*)&sBlo[ch * 8];
                }
#pragma unroll
                for (int fm = 0; fm < 4; ++fm) {
                    int rA = wr * 64 + fm * 16 + l15;
                    int ch = (rA * 8 + ks * 4 + lhi) ^ (rA & 7);
                    bf16x8 ah = *(const bf16x8*)&sAhi[ch * 8];
                    bf16x8 al = *(const bf16x8*)&sAlo[ch * 8];
#pragma unroll
                    for (int fn = 0; fn < 4; ++fn) {
                        acc[fm][fn] = __builtin_amdgcn_mfma_f32_16x16x32_bf16(ah, bh[fn], acc[fm][fn], 0, 0, 0);
                        acc[fm][fn] = __builtin_amdgcn_mfma_f32_16x16x32_bf16(ah, bl[fn], acc[fm][fn], 0, 0, 0);
                        acc[fm][fn] = __builtin_amdgcn_mfma_f32_16x16x32_bf16(al, bh[fn], acc[fm][fn], 0, 0, 0);
                    }
                }
            }
        }

        int n0 = nb * 128;
#pragma unroll
        for (int fn = 0; fn < 4; ++fn) {
            int n = n0 + wc * 64 + fn * 16 + l15;
            float hbv = hp[b * H_ + n] + bias[n];
            float vvv = V[n];
#pragma unroll
            for (int fm = 0; fm < 4; ++fm) {
                f32x4 a = acc[fm][fn];
#pragma unroll
                for (int rg = 0; rg < 4; ++rg)
                    rowsum[fm][rg] += tanh_fast(a[rg] + hbv) * vvv;
            }
        }
    }

    __syncthreads();
    float* s_red = (float*)smem;
#pragma unroll
    for (int fm = 0; fm < 4; ++fm)
#pragma unroll
        for (int rg = 0; rg < 4; ++rg) {
            float v = rowsum[fm][rg];
            v += __shfl_xor(v, 1, 16);
            v += __shfl_xor(v, 2, 16);
            v += __shfl_xor(v, 4, 16);
            v += __shfl_xor(v, 8, 16);
            if (l15 == 0)
                s_red[wc * 128 + wr * 64 + fm * 16 + lhi * 4 + rg] = v;
        }
    __syncthreads();
    if (tid < 128) {
        int m = m0 + tid;
        float sc = s_red[tid] + s_red[128 + tid];
        scores_out[m] = (mask[m] == 1) ? sc : NEGV;
    }
#undef STAGE_LOAD
#undef STAGE_WRITE
}

__global__ __launch_bounds__(256) void k_softmax(const float* __restrict__ scores,
                                                 float* __restrict__ weights) {
    __shared__ float red[8];
    int b = blockIdx.x;
    int tid = threadIdx.x;
    const float* srow = scores + b * S_;
    float vals[8];
    float mx = -INFINITY;
#pragma unroll
    for (int i = 0; i < 8; ++i) {
        vals[i] = srow[tid + i * 256];
        mx = fmaxf(mx, vals[i]);
    }
    for (int off = 32; off; off >>= 1) mx = fmaxf(mx, __shfl_xor(mx, off, 64));
    int wave = tid >> 6;
    if ((tid & 63) == 0) red[wave] = mx;
    __syncthreads();
    mx = fmaxf(fmaxf(red[0], red[1]), fmaxf(red[2], red[3]));
    float sum = 0.f;
#pragma unroll
    for (int i = 0; i < 8; ++i) {
        vals[i] = expf(vals[i] - mx);
        sum += vals[i];
    }
    for (int off = 32; off; off >>= 1) sum += __shfl_xor(sum, off, 64);
    if ((tid & 63) == 0) red[4 + wave] = sum;
    __syncthreads();
    sum = red[4] + red[5] + red[6] + red[7];
    float inv = 1.f / sum;
#pragma unroll
    for (int i = 0; i < 8; ++i)
        weights[b * S_ + tid + i * 256] = vals[i] * inv;
}

extern "C" void kernel_launch(void* const* d_in, const int* in_sizes, int n_in,
                              void* d_out, int out_size, void* d_ws, size_t ws_size,
                              hipStream_t stream) {
    const float* ls   = (const float*)d_in[0];
    const float* enc  = (const float*)d_in[1];
    const int*   mask = (const int*)d_in[2];
    const float* W    = (const float*)d_in[3];
    const float* bias = (const float*)d_in[4];
    const float* V    = (const float*)d_in[5];

    float* out     = (float*)d_out;
    float* ctx     = out;
    float* weights = out + 32768;
    float* scores  = out + 98304;

    // fast path: Wf16(2MB) hp(128KB) spart(1MB) part(2MB) = ~5.3MB
    const size_t need = 2097152ull + 131072ull + 1048576ull + 2097152ull;

    if (ws_size >= need) {
        unsigned short* Wf16 = (unsigned short*)d_ws;         // 1Mi halves
        float* hp    = (float*)(Wf16 + 1048576);
        float* spart = hp + 32768;              // 4 * 65536 floats
        float* part  = spart + 262144;          // 512 * 1024 floats

        hipFuncSetAttribute((const void*)k_scores_occ,
                            hipFuncAttributeMaxDynamicSharedMemorySize, 49152);

        k_prep<<<640, 256, 0, stream>>>(W, ls, Wf16, hp);
        k_scores_occ<<<2048, 512, 49152, stream>>>(enc, Wf16, hp, bias, V, spart);
        k_softmax_fold<<<32, 256, 0, stream>>>(spart, mask, scores, weights);
        k_ctx_partial_f32<<<512, 256, 0, stream>>>(weights, enc, part);
        k_ctx_reduce<<<128, 256, 0, stream>>>(part, ctx);
    } else {
        unsigned short* Whi = (unsigned short*)d_ws;
        unsigned short* Wlo = Whi + 1048576;
        float* hp   = (float*)(Wlo + 1048576);
        float* part = hp + 32768;

        k_splitW_lin<<<512, 256, 0, stream>>>(W, Whi, Wlo);
        k_hpart_fb<<<128, 256, 0, stream>>>(ls, W, hp);
        k_scores_mfma_fb<<<512, 256, 0, stream>>>(enc, Whi, Wlo, hp, bias, V, mask, scores);
        k_softmax<<<32, 256, 0, stream>>>(scores, weights);
        k_ctx_partial_f32<<<512, 256, 0, stream>>>(weights, enc, part);
        k_ctx_reduce<<<128, 256, 0, stream>>>(part, ctx);
    }
}